// Round 9
// baseline (158.145 us; speedup 1.0000x reference)
//
#include <hip/hip_runtime.h>

typedef short bf8 __attribute__((ext_vector_type(8)));   // 8 bf16 in 4 VGPRs
typedef float f32x4 __attribute__((ext_vector_type(4)));
typedef float f32x16 __attribute__((ext_vector_type(16)));
typedef int i32x4 __attribute__((ext_vector_type(4)));

__device__ __forceinline__ ushort f2b(float f) {
  unsigned x = __builtin_bit_cast(unsigned, f);
  unsigned r = (x + 0x7fffu + ((x >> 16) & 1u)) >> 16;
  return (ushort)r;
}
__device__ __forceinline__ float b2f(ushort u) {
  unsigned x = ((unsigned)u) << 16;
  return __builtin_bit_cast(float, x);
}

__device__ __forceinline__ f32x4 mfma16(bf8 a, bf8 b, f32x4 c) {
  return __builtin_amdgcn_mfma_f32_16x16x32_bf16(a, b, c, 0, 0, 0);
}
__device__ __forceinline__ f32x16 mfma32(bf8 a, bf8 b, f32x16 c) {
  return __builtin_amdgcn_mfma_f32_32x32x16_bf16(a, b, c, 0, 0, 0);
}

__device__ __forceinline__ float fexp2(float x) {
#if __has_builtin(__builtin_amdgcn_exp2f)
  return __builtin_amdgcn_exp2f(x);
#else
  return exp2f(x);
#endif
}

__device__ __forceinline__ uint cvtpk(float lo, float hi_) {
  uint r;
  asm("v_cvt_pk_bf16_f32 %0, %1, %2" : "=v"(r) : "v"(lo), "v"(hi_));
  return r;
}
__device__ __forceinline__ void plswap(uint& a, uint& b) {
  asm("v_permlane32_swap_b32 %0, %1" : "+v"(a), "+v"(b));
}

__device__ __forceinline__ void gload16(const ushort* g, ushort* l) {
  __builtin_amdgcn_global_load_lds(
      (const __attribute__((address_space(1))) void*)g,
      (__attribute__((address_space(3))) void*)l, 16, 0, 0);
}

// ---------------- cast x (f32 -> bf16) ----------------
__global__ __launch_bounds__(256) void cast_x(const float* __restrict__ in,
                                              ushort* __restrict__ out) {
  const int i = (blockIdx.x * 256 + threadIdx.x) * 4;
  float4 v = *(const float4*)(in + i);
  ushort4 o;
  o.x = f2b(v.x); o.y = f2b(v.y); o.z = f2b(v.z); o.w = f2b(v.w);
  *(ushort4*)(out + i) = o;
}

// ------- transpose weight [K=1024][N] f32 -> [N][1024] bf16 -------
__global__ void trans_w(const float* __restrict__ in, ushort* __restrict__ out,
                        int N) {
  __shared__ float tile[32][33];
  const int kx = blockIdx.x * 32, nx = blockIdx.y * 32;
  const int tx = threadIdx.x, ty = threadIdx.y;
#pragma unroll
  for (int i = ty; i < 32; i += 8)
    tile[i][tx] = in[(size_t)(kx + i) * N + nx + tx];
  __syncthreads();
#pragma unroll
  for (int i = ty; i < 32; i += 8)
    out[(size_t)(nx + i) * 1024 + kx + tx] = f2b(tile[tx][i]);
}

// ---------------- GEMM C[M][N] = A[M][K] * Bt[N][K]^T ----------------
template <bool OUT_BF16>
__global__ __launch_bounds__(256) void gemm_bt(const ushort* __restrict__ A,
                                               const ushort* __restrict__ Bt,
                                               void* __restrict__ Cv, int M,
                                               int N, int K) {
  __shared__ ushort aL[128 * 32];
  __shared__ ushort bL[128 * 32];
  const int tid = threadIdx.x;
  const int wid = tid >> 6, lane = tid & 63;
  const int l15 = lane & 15, l4 = lane >> 4;
  const int bm = blockIdx.y * 128, bn = blockIdx.x * 128;
  const int wr = (wid >> 1) * 64, wc = (wid & 1) * 64;
  f32x4 acc[4][4] = {};
  for (int kb = 0; kb < K; kb += 32) {
    __syncthreads();
#pragma unroll
    for (int i = 0; i < 2; ++i) {
      const int e = (i * 256 + tid) * 8;
      const int r = e >> 5, c = e & 31;
      gload16(A + (size_t)(bm + r) * K + kb + c, &aL[i * 2048 + wid * 512]);
      gload16(Bt + (size_t)(bn + r) * K + kb + c, &bL[i * 2048 + wid * 512]);
    }
    asm volatile("s_waitcnt vmcnt(0)" ::: "memory");
    __syncthreads();
    bf8 af[4], bfr[4];
#pragma unroll
    for (int i = 0; i < 4; ++i) {
      af[i] = *(const bf8*)&aL[(wr + i * 16 + l15) * 32 + l4 * 8];
      bfr[i] = *(const bf8*)&bL[(wc + i * 16 + l15) * 32 + l4 * 8];
    }
#pragma unroll
    for (int i = 0; i < 4; ++i)
#pragma unroll
      for (int j = 0; j < 4; ++j)
        acc[i][j] = mfma16(af[i], bfr[j], acc[i][j]);
  }
#pragma unroll
  for (int i = 0; i < 4; ++i)
#pragma unroll
    for (int j = 0; j < 4; ++j)
#pragma unroll
      for (int r = 0; r < 4; ++r) {
        const size_t row = bm + wr + i * 16 + l4 * 4 + r;
        const size_t col = bn + wc + j * 16 + l15;
        if constexpr (OUT_BF16)
          ((ushort*)Cv)[row * N + col] = f2b(acc[i][j][r]);
        else
          ((float*)Cv)[row * N + col] = acc[i][j][r];
      }
}

// ---------------- RoPE for Q,K (reads fused qkv bf16) ----------------
// Q is pre-scaled by 0.125*log2(e) so attention scores are in log2 domain.
__global__ __launch_bounds__(256) void rope_qk(const ushort* __restrict__ qkv,
                                               const float* __restrict__ fc,
                                               const float* __restrict__ fs,
                                               ushort* __restrict__ qh,
                                               ushort* __restrict__ kh) {
  const int idx = blockIdx.x * 256 + threadIdx.x;  // 4096*640 total
  const int u = idx % 640;
  const int m = idx / 640;
  const int s = m & 2047, b = m >> 11;
  int col, j;
  if (u < 512) {
    j = u & 31;
    col = (u >> 5) * 64 + 2 * j;
  } else {
    j = (u - 512) & 31;
    col = 1024 + ((u - 512) >> 5) * 64 + 2 * j;
  }
  const uint pr = *(const uint*)(qkv + (size_t)m * 1536 + col);
  const float tr = b2f((ushort)(pr & 0xffff));
  const float ti = b2f((ushort)(pr >> 16));
  const float c = fc[s * 32 + j], sn = fs[s * 32 + j];
  float orr = tr * c - ti * sn;
  float oi = tr * sn + ti * c;
  if (u < 512) {
    orr *= 0.18033688f;  // (1/sqrt(64)) * log2(e)
    oi *= 0.18033688f;
    const uint w = (uint)f2b(orr) | ((uint)f2b(oi) << 16);
    *(uint*)(qh + ((size_t)(b * 16 + (u >> 5)) * 2048 + s) * 64 + 2 * j) = w;
  } else {
    const uint w = (uint)f2b(orr) | ((uint)f2b(oi) << 16);
    const int kv = (u - 512) >> 5;
    *(uint*)(kh + ((size_t)(b * 4 + kv) * 2048 + s) * 64 + 2 * j) = w;
  }
}

// ---------------- V transpose: qkv cols 1280.. -> vT[b*4+kv][64][2048] ----
__global__ __launch_bounds__(256) void vtrans(const ushort* __restrict__ qkv,
                                              ushort* __restrict__ vT) {
  __shared__ ushort tile[64][65];
  const int id = blockIdx.x;  // B*KVH*32 = 256
  const int st = id & 31, kv = (id >> 5) & 3, b = id >> 7;
  const int tid = threadIdx.x;
  for (int e = tid; e < 4096; e += 256) {
    const int r = e >> 6, c = e & 63;
    tile[r][c] =
        qkv[(size_t)(b * 2048 + st * 64 + r) * 1536 + 1280 + kv * 64 + c];
  }
  __syncthreads();
  for (int e = tid; e < 4096; e += 256) {
    const int d = e >> 6, c = e & 63;
    vT[((size_t)(b * 4 + kv) * 64 + d) * 2048 + st * 64 + c] = tile[c][d];
  }
}

// ---------------- Flash attention v5: 4 waves, KV-split pairs -------------
// 512 blocks x 256 thr. Block = (bh, pair (tA=pr, tB=31-pr)). Two wave-pairs
// split each phase's KV range (lo pair first half, hi pair rest). Fixed-max
// softmax makes partials additive: O=O_lo+O_hi, l=l_lo+l_hi (no rescale).
// Every block runs exactly ceil(nA/2)+ceil(nB/2)=17 iterations -> uniform
// blocks, 2 blocks/CU, 8 waves/CU (2/SIMD).

#define MCONST 12.0f

__device__ __forceinline__ void astep2(const bf8 (&kfA)[4], const bf8 (&kfB)[4],
                                       const bf8 (&vfA)[4], const bf8 (&vfB)[4],
                                       const bf8 (&qf)[4], f32x16& o0,
                                       f32x16& o1, float& l, int k0, int qg,
                                       bool maskt, int hi) {
  f32x16 s0 = {}, s1 = {};
  __builtin_amdgcn_s_setprio(1);
#pragma unroll
  for (int ks = 0; ks < 4; ++ks) s0 = mfma32(kfA[ks], qf[ks], s0);
#pragma unroll
  for (int ks = 0; ks < 4; ++ks) s1 = mfma32(kfB[ks], qf[ks], s1);
  __builtin_amdgcn_s_setprio(0);
  if (maskt) {
#pragma unroll
    for (int r = 0; r < 16; ++r) {
      const int key = k0 + (r & 3) + 8 * (r >> 2) + 4 * hi;
      if (key > qg) s0[r] = -1e30f;
      if (key + 32 > qg) s1[r] = -1e30f;
    }
  }
  float t[16];
#pragma unroll
  for (int r = 0; r < 16; ++r) {
    s0[r] = fexp2(s0[r] - MCONST);
    s1[r] = fexp2(s1[r] - MCONST);
    t[r] = s0[r] + s1[r];
  }
#pragma unroll
  for (int st = 8; st > 0; st >>= 1)
#pragma unroll
    for (int r = 0; r < st; ++r) t[r] += t[r + st];
  l += t[0] + __shfl_xor(t[0], 32);
  bf8 pa[4];
  {
    uint a0 = cvtpk(s0[0], s0[1]), a1 = cvtpk(s0[2], s0[3]);
    uint b0 = cvtpk(s0[4], s0[5]), b1 = cvtpk(s0[6], s0[7]);
    plswap(a0, b0);
    plswap(a1, b1);
    i32x4 w = {(int)a0, (int)a1, (int)b0, (int)b1};
    pa[0] = __builtin_bit_cast(bf8, w);
    uint c0 = cvtpk(s0[8], s0[9]), c1 = cvtpk(s0[10], s0[11]);
    uint d0 = cvtpk(s0[12], s0[13]), d1 = cvtpk(s0[14], s0[15]);
    plswap(c0, d0);
    plswap(c1, d1);
    i32x4 w2 = {(int)c0, (int)c1, (int)d0, (int)d1};
    pa[1] = __builtin_bit_cast(bf8, w2);
  }
  {
    uint a0 = cvtpk(s1[0], s1[1]), a1 = cvtpk(s1[2], s1[3]);
    uint b0 = cvtpk(s1[4], s1[5]), b1 = cvtpk(s1[6], s1[7]);
    plswap(a0, b0);
    plswap(a1, b1);
    i32x4 w = {(int)a0, (int)a1, (int)b0, (int)b1};
    pa[2] = __builtin_bit_cast(bf8, w);
    uint c0 = cvtpk(s1[8], s1[9]), c1 = cvtpk(s1[10], s1[11]);
    uint d0 = cvtpk(s1[12], s1[13]), d1 = cvtpk(s1[14], s1[15]);
    plswap(c0, d0);
    plswap(c1, d1);
    i32x4 w2 = {(int)c0, (int)c1, (int)d0, (int)d1};
    pa[3] = __builtin_bit_cast(bf8, w2);
  }
  __builtin_amdgcn_s_setprio(1);
#pragma unroll
  for (int ks = 0; ks < 4; ++ks) o0 = mfma32(vfA[ks], pa[ks], o0);
#pragma unroll
  for (int ks = 0; ks < 4; ++ks) o1 = mfma32(vfB[ks], pa[ks], o1);
  __builtin_amdgcn_s_setprio(0);
}

__device__ __forceinline__ void tile_out(ushort* ow, const f32x16& o0,
                                         const f32x16& o1, float l, int b,
                                         int h, int qw, int l31, int hi,
                                         int lane, ushort* ao) {
  const float inv = 1.0f / l;
#pragma unroll
  for (int dt = 0; dt < 2; ++dt)
#pragma unroll
    for (int rq = 0; rq < 4; ++rq) {
      const f32x16& ac = dt ? o1 : o0;
      uint2 w;
      w.x = (uint)f2b(ac[rq * 4 + 0] * inv) |
            ((uint)f2b(ac[rq * 4 + 1] * inv) << 16);
      w.y = (uint)f2b(ac[rq * 4 + 2] * inv) |
            ((uint)f2b(ac[rq * 4 + 3] * inv) << 16);
      const int d = dt * 32 + 8 * rq + 4 * hi;
      *(uint2*)&ow[l31 * 68 + d] = w;
    }
  asm volatile("s_waitcnt lgkmcnt(0)" ::: "memory");
  __builtin_amdgcn_sched_barrier(0);
  const int rrow = lane >> 4;
  const int rcol = (lane & 15) * 4;
  const size_t gbase = ((size_t)b * 2048 + qw) * 1024 + h * 64;
#pragma unroll
  for (int i = 0; i < 8; ++i) {
    const int rw = i * 4 + rrow;
    uint2 v = *(const uint2*)&ow[rw * 68 + rcol];
    *(uint2*)&ao[gbase + (size_t)rw * 1024 + rcol] = v;
  }
}

__global__ __launch_bounds__(256) void attn_fwd(const ushort* __restrict__ qh,
                                                const ushort* __restrict__ kh,
                                                const ushort* __restrict__ vT,
                                                ushort* __restrict__ ao) {
  __shared__ ushort kls[2][2][4096];  // [pair][parity] K tiles (swizzled)
  __shared__ ushort vls[2][2][4096];  // [pair][parity] V tiles (swizzled)
  __shared__ char ubuf[8704] __attribute__((aligned(16)));  // merge ∪ olds
  __shared__ float lsh[64];
  const int tid = threadIdx.x;
  const int wid = tid >> 6, lane = tid & 63;
  const int pairid = wid >> 1, wq = wid & 1;
  const int l31 = lane & 31, hi = lane >> 5;
  const int gid = blockIdx.x;  // 512
  const int bh = gid & 31;
  const int pr = gid >> 5;  // 0..15
  const int b = bh >> 4, h = bh & 15;
  const int kv = h >> 2;
  const int tA = pr, tB = 31 - pr;
  const int nA = tA + 1, nB = tB + 1;  // nA+nB = 33
  const int nA2 = nA >> 1, nB2 = nB >> 1;
  const int itA = nA - nA2, itB = nB - nB2;  // itA+itB = 17 always
  const int loA = pairid ? nA2 : 0;
  const int cntA = pairid ? (nA - nA2) : nA2;
  const int loB = pairid ? nB2 : 0;
  const int cntB = pairid ? (nB - nB2) : nB2;

  const ushort* kbase = kh + (size_t)(b * 4 + kv) * 2048 * 64;
  const ushort* vbase = vT + (size_t)(b * 4 + kv) * 64 * 2048;
  float* umrg = (float*)ubuf;

  auto slotTile = [&](int j, bool& valid) -> int {
    if (j < itA) {
      valid = j < cntA;
      return loA + j;
    }
    const int jb = j - itA;
    valid = (jb < cntB) && (j < itA + itB);
    return loB + jb;
  };
  auto stage = [&](int parity, int k0) {
    ushort* kbuf = kls[pairid][parity];
    ushort* vbuf = vls[pairid][parity];
#pragma unroll
    for (int jj = 0; jj < 4; ++jj) {
      const int i = wq * 256 + jj * 64 + lane;
      const int r = i >> 3, s = i & 7;
      const int sw = (s ^ (r & 7)) << 3;
      gload16(kbase + (size_t)(k0 + r) * 64 + sw, kbuf + (wq * 4 + jj) * 512);
      gload16(vbase + (size_t)r * 2048 + k0 + sw, vbuf + (wq * 4 + jj) * 512);
    }
  };
  auto loadQ = [&](int t, bf8(&qf)[4]) {
    const ushort* qb =
        qh + ((size_t)bh * 2048 + t * 64 + wq * 32 + l31) * 64 + hi * 8;
#pragma unroll
    for (int ks = 0; ks < 4; ++ks) qf[ks] = *(const bf8*)(qb + ks * 16);
  };
  auto bsync = [&]() {
    asm volatile("s_waitcnt lgkmcnt(0)" ::: "memory");
    __builtin_amdgcn_s_barrier();
    asm volatile("" ::: "memory");
  };

  bf8 qf[4];
  loadQ(tA, qf);
  f32x16 o0 = {}, o1 = {};
  float l = 0.f;

  {
    bool v;
    const int t0 = slotTile(0, v);
    if (v) stage(0, t0 * 64);
  }

  int j = 0;
#pragma unroll 1
  for (int phase = 0; phase < 2; ++phase) {
    const int iters = phase ? itB : itA;
    const int nPh = phase ? nB : nA;
    const int qg = (phase ? tB : tA) * 64 + wq * 32 + l31;
#pragma unroll 1
    for (int it = 0; it < iters; ++it, ++j) {
      bool valid;
      const int tile = slotTile(j, valid);
      asm volatile("s_waitcnt vmcnt(0)" ::: "memory");
      __builtin_amdgcn_s_barrier();
      asm volatile("" ::: "memory");
      bf8 kfA[4], kfB[4], vfA[4], vfB[4];
      const ushort* kb_l = kls[pairid][j & 1];
      const ushort* vb_l = vls[pairid][j & 1];
      const int sw0 = l31 & 7;
      if (valid) {
#pragma unroll
        for (int ks = 0; ks < 4; ++ks) {
          const int c2 = 2 * ks + hi;
          const int off = (c2 ^ sw0) << 3;
          kfA[ks] = *(const bf8*)&kb_l[l31 * 64 + off];
          kfB[ks] = *(const bf8*)&kb_l[(32 + l31) * 64 + off];
          vfA[ks] = *(const bf8*)&vb_l[l31 * 64 + off];
          vfB[ks] = *(const bf8*)&vb_l[(32 + l31) * 64 + off];
        }
      }
      asm volatile("s_waitcnt lgkmcnt(0)" ::: "memory");
      __builtin_amdgcn_sched_barrier(0);
      __builtin_amdgcn_s_barrier();
      {
        bool vn;
        const int tn = slotTile(j + 1, vn);
        if (vn) stage((j + 1) & 1, tn * 64);
      }
      if (valid)
        astep2(kfA, kfB, vfA, vfB, qf, o0, o1, l, tile * 64, qg,
               tile == nPh - 1, hi);
    }
    // ---- merge partials (additive under fixed-max) + output by lo pair ----
    const int mbase = wq * 1024 + lane * 16;
    if (pairid) {
#pragma unroll
      for (int r = 0; r < 16; ++r) umrg[mbase + (r ^ (lane & 15))] = o0[r];
      lsh[wq * 32 + l31] = l;
    }
    bsync();
    if (!pairid) {
#pragma unroll
      for (int r = 0; r < 16; ++r) o0[r] += umrg[mbase + (r ^ (lane & 15))];
    }
    bsync();
    if (pairid) {
#pragma unroll
      for (int r = 0; r < 16; ++r) umrg[mbase + (r ^ (lane & 15))] = o1[r];
    }
    bsync();
    if (!pairid) {
#pragma unroll
      for (int r = 0; r < 16; ++r) o1[r] += umrg[mbase + (r ^ (lane & 15))];
      l += lsh[wq * 32 + l31];
    }
    bsync();
    if (!pairid) {
      tile_out((ushort*)ubuf + wq * 2176, o0, o1, l, b, h,
               (phase ? tB : tA) * 64 + wq * 32, l31, hi, lane, ao);
    }
    if (phase == 0) {
#pragma unroll
      for (int e = 0; e < 16; ++e) {
        o0[e] = 0.f;
        o1[e] = 0.f;
      }
      l = 0.f;
      loadQ(tB, qf);
    }
  }
}

extern "C" void kernel_launch(void* const* d_in, const int* in_sizes, int n_in,
                              void* d_out, int out_size, void* d_ws,
                              size_t ws_size, hipStream_t stream) {
  (void)in_sizes; (void)n_in; (void)out_size; (void)ws_size;
  const float* x = (const float*)d_in[0];
  const float* wq = (const float*)d_in[1];
  const float* wk = (const float*)d_in[2];
  const float* wv = (const float*)d_in[3];
  const float* wo = (const float*)d_in[4];
  const float* fc = (const float*)d_in[5];
  const float* fs = (const float*)d_in[6];
  float* out = (float*)d_out;

  ushort* xb = (ushort*)d_ws;               // 4096x1024
  ushort* wqkvT = xb + 4194304;             // 1536x1024
  ushort* woT = wqkvT + 1572864;            // 1024x1024
  ushort* qkv = woT + 1048576;              // 4096x1536
  ushort* qh = qkv + 6291456;               // 32x2048x64
  ushort* kh = qh + 4194304;                // 8x2048x64
  ushort* vTb = kh + 1048576;               // 8x64x2048
  ushort* ao = vTb + 1048576;               // 4096x1024

  cast_x<<<4096, 256, 0, stream>>>(x, xb);
  dim3 tb(32, 8);
  trans_w<<<dim3(32, 32), tb, 0, stream>>>(wq, wqkvT, 1024);
  trans_w<<<dim3(32, 8), tb, 0, stream>>>(wk, wqkvT + 1024 * 1024, 256);
  trans_w<<<dim3(32, 8), tb, 0, stream>>>(wv, wqkvT + 1280 * 1024, 256);
  trans_w<<<dim3(32, 32), tb, 0, stream>>>(wo, woT, 1024);
  gemm_bt<true><<<dim3(12, 32), 256, 0, stream>>>(xb, wqkvT, qkv, 4096, 1536, 1024);
  rope_qk<<<10240, 256, 0, stream>>>(qkv, fc, fs, qh, kh);
  vtrans<<<256, 256, 0, stream>>>(qkv, vTb);
  attn_fwd<<<512, 256, 0, stream>>>(qh, kh, vTb, ao);
  gemm_bt<false><<<dim3(8, 32), 256, 0, stream>>>(ao, woT, out, 4096, 1024, 1024);
}

// Round 10
// 123.529 us; speedup vs baseline: 1.2802x; 1.2802x over previous
//
#include <hip/hip_runtime.h>

typedef short bf8 __attribute__((ext_vector_type(8)));   // 8 bf16 in 4 VGPRs
typedef float f32x4 __attribute__((ext_vector_type(4)));
typedef float f32x16 __attribute__((ext_vector_type(16)));
typedef int i32x4 __attribute__((ext_vector_type(4)));

__device__ __forceinline__ ushort f2b(float f) {
  unsigned x = __builtin_bit_cast(unsigned, f);
  unsigned r = (x + 0x7fffu + ((x >> 16) & 1u)) >> 16;
  return (ushort)r;
}
__device__ __forceinline__ float b2f(ushort u) {
  unsigned x = ((unsigned)u) << 16;
  return __builtin_bit_cast(float, x);
}

__device__ __forceinline__ f32x4 mfma16(bf8 a, bf8 b, f32x4 c) {
  return __builtin_amdgcn_mfma_f32_16x16x32_bf16(a, b, c, 0, 0, 0);
}
__device__ __forceinline__ f32x16 mfma32(bf8 a, bf8 b, f32x16 c) {
  return __builtin_amdgcn_mfma_f32_32x32x16_bf16(a, b, c, 0, 0, 0);
}

__device__ __forceinline__ float fexp2(float x) {
#if __has_builtin(__builtin_amdgcn_exp2f)
  return __builtin_amdgcn_exp2f(x);
#else
  return exp2f(x);
#endif
}

__device__ __forceinline__ uint cvtpk(float lo, float hi_) {
  uint r;
  asm("v_cvt_pk_bf16_f32 %0, %1, %2" : "=v"(r) : "v"(lo), "v"(hi_));
  return r;
}
__device__ __forceinline__ void plswap(uint& a, uint& b) {
  asm("v_permlane32_swap_b32 %0, %1" : "+v"(a), "+v"(b));
}

__device__ __forceinline__ void gload16(const ushort* g, ushort* l) {
  __builtin_amdgcn_global_load_lds(
      (const __attribute__((address_space(1))) void*)g,
      (__attribute__((address_space(3))) void*)l, 16, 0, 0);
}

// ---------------- prep1: cast x (f32->bf16) + all weight transposes ------
__global__ __launch_bounds__(256) void prep1(
    const float* __restrict__ x, const float* __restrict__ wq,
    const float* __restrict__ wk, const float* __restrict__ wv,
    const float* __restrict__ wo, ushort* __restrict__ xb,
    ushort* __restrict__ wqkvT, ushort* __restrict__ woT) {
  __shared__ float tile[32][33];
  const int bid = blockIdx.x;
  if (bid < 4096) {
    const int i = (bid * 256 + threadIdx.x) * 4;
    float4 v = *(const float4*)(x + i);
    ushort4 o;
    o.x = f2b(v.x); o.y = f2b(v.y); o.z = f2b(v.z); o.w = f2b(v.w);
    *(ushort4*)(xb + i) = o;
    return;
  }
  int t = bid - 4096;  // 0..2559
  const float* src;
  ushort* dst;
  int N;
  if (t < 1024) {
    src = wq; dst = wqkvT; N = 1024;
  } else if (t < 1280) {
    src = wk; dst = wqkvT + 1024 * 1024; N = 256; t -= 1024;
  } else if (t < 1536) {
    src = wv; dst = wqkvT + 1280 * 1024; N = 256; t -= 1280;
  } else {
    src = wo; dst = woT; N = 1024; t -= 1536;
  }
  const int kx = (t & 31) * 32, nx = (t >> 5) * 32;
  const int tx = threadIdx.x & 31, ty = threadIdx.x >> 5;
#pragma unroll
  for (int i = ty; i < 32; i += 8)
    tile[i][tx] = src[(size_t)(kx + i) * N + nx + tx];
  __syncthreads();
#pragma unroll
  for (int i = ty; i < 32; i += 8)
    dst[(size_t)(nx + i) * 1024 + kx + tx] = f2b(tile[tx][i]);
}

// ---------------- GEMM C[M][N] = A[M][K] * Bt[N][K]^T ----------------
template <bool OUT_BF16>
__global__ __launch_bounds__(256) void gemm_bt(const ushort* __restrict__ A,
                                               const ushort* __restrict__ Bt,
                                               void* __restrict__ Cv, int M,
                                               int N, int K) {
  __shared__ ushort aL[128 * 32];
  __shared__ ushort bL[128 * 32];
  const int tid = threadIdx.x;
  const int wid = tid >> 6, lane = tid & 63;
  const int l15 = lane & 15, l4 = lane >> 4;
  const int bm = blockIdx.y * 128, bn = blockIdx.x * 128;
  const int wr = (wid >> 1) * 64, wc = (wid & 1) * 64;
  f32x4 acc[4][4] = {};
  for (int kb = 0; kb < K; kb += 32) {
    __syncthreads();
#pragma unroll
    for (int i = 0; i < 2; ++i) {
      const int e = (i * 256 + tid) * 8;
      const int r = e >> 5, c = e & 31;
      gload16(A + (size_t)(bm + r) * K + kb + c, &aL[i * 2048 + wid * 512]);
      gload16(Bt + (size_t)(bn + r) * K + kb + c, &bL[i * 2048 + wid * 512]);
    }
    asm volatile("s_waitcnt vmcnt(0)" ::: "memory");
    __syncthreads();
    bf8 af[4], bfr[4];
#pragma unroll
    for (int i = 0; i < 4; ++i) {
      af[i] = *(const bf8*)&aL[(wr + i * 16 + l15) * 32 + l4 * 8];
      bfr[i] = *(const bf8*)&bL[(wc + i * 16 + l15) * 32 + l4 * 8];
    }
#pragma unroll
    for (int i = 0; i < 4; ++i)
#pragma unroll
      for (int j = 0; j < 4; ++j)
        acc[i][j] = mfma16(af[i], bfr[j], acc[i][j]);
  }
#pragma unroll
  for (int i = 0; i < 4; ++i)
#pragma unroll
    for (int j = 0; j < 4; ++j)
#pragma unroll
      for (int r = 0; r < 4; ++r) {
        const size_t row = bm + wr + i * 16 + l4 * 4 + r;
        const size_t col = bn + wc + j * 16 + l15;
        if constexpr (OUT_BF16)
          ((ushort*)Cv)[row * N + col] = f2b(acc[i][j][r]);
        else
          ((float*)Cv)[row * N + col] = acc[i][j][r];
      }
}

// ---------------- prep2: RoPE for Q,K + V transpose ----------------
// Q is pre-scaled by 0.125*log2(e) so attention scores are in log2 domain.
__global__ __launch_bounds__(256) void prep2(const ushort* __restrict__ qkv,
                                             const float* __restrict__ fc,
                                             const float* __restrict__ fs,
                                             ushort* __restrict__ qh,
                                             ushort* __restrict__ kh,
                                             ushort* __restrict__ vT) {
  __shared__ ushort tile[64][65];
  if (blockIdx.x < 10240) {
    const int idx = blockIdx.x * 256 + threadIdx.x;  // 4096*640 total
    const int u = idx % 640;
    const int m = idx / 640;
    const int s = m & 2047, b = m >> 11;
    int col, j;
    if (u < 512) {
      j = u & 31;
      col = (u >> 5) * 64 + 2 * j;
    } else {
      j = (u - 512) & 31;
      col = 1024 + ((u - 512) >> 5) * 64 + 2 * j;
    }
    const uint pr = *(const uint*)(qkv + (size_t)m * 1536 + col);
    const float tr = b2f((ushort)(pr & 0xffff));
    const float ti = b2f((ushort)(pr >> 16));
    const float c = fc[s * 32 + j], sn = fs[s * 32 + j];
    float orr = tr * c - ti * sn;
    float oi = tr * sn + ti * c;
    if (u < 512) {
      orr *= 0.18033688f;  // (1/sqrt(64)) * log2(e)
      oi *= 0.18033688f;
      const uint w = (uint)f2b(orr) | ((uint)f2b(oi) << 16);
      *(uint*)(qh + ((size_t)(b * 16 + (u >> 5)) * 2048 + s) * 64 + 2 * j) = w;
    } else {
      const uint w = (uint)f2b(orr) | ((uint)f2b(oi) << 16);
      const int kv = (u - 512) >> 5;
      *(uint*)(kh + ((size_t)(b * 4 + kv) * 2048 + s) * 64 + 2 * j) = w;
    }
    return;
  }
  // V transpose: 256 blocks
  const int id = blockIdx.x - 10240;
  const int st = id & 31, kv = (id >> 5) & 3, b = id >> 7;
  const int tid = threadIdx.x;
  for (int e = tid; e < 4096; e += 256) {
    const int r = e >> 6, c = e & 63;
    tile[r][c] =
        qkv[(size_t)(b * 2048 + st * 64 + r) * 1536 + 1280 + kv * 64 + c];
  }
  __syncthreads();
  for (int e = tid; e < 4096; e += 256) {
    const int d = e >> 6, c = e & 63;
    vT[((size_t)(b * 4 + kv) * 64 + d) * 2048 + st * 64 + c] = tile[c][d];
  }
}

// ---------------- Flash attention v6: 1-wave blocks, barrier-free ---------
// 2048 blocks x 64 thr; block = (bh, t) one 32-row q-tile, t = gid>>5 so a
// CU's stride-256 block set spans t in {t0, t0+8, ..} (balanced ~1.10).
// Single-buffered LDS KV (16KB) with issue-early staging: ds_reads drain,
// next stage issues, compute covers L2 latency; vmcnt(0) at loop top.
// NO s_barrier anywhere. Fixed-max softmax (log2 domain, shift 12).
// S^T = mfma(K, Q): lane holds q = lane&31, 16 keys at crow(r,hi).
// O^T = mfma(V^T, P^T): lane holds q = lane&31, d = dt*32 + crow(r,hi).

#define MCONST 12.0f

__device__ __forceinline__ void astep2(const bf8 (&kfA)[4], const bf8 (&kfB)[4],
                                       const bf8 (&vfA)[4], const bf8 (&vfB)[4],
                                       const bf8 (&qf)[4], f32x16& o0,
                                       f32x16& o1, float& l, int k0, int qg,
                                       bool maskt, int hi) {
  f32x16 s0 = {}, s1 = {};
  __builtin_amdgcn_s_setprio(1);
#pragma unroll
  for (int ks = 0; ks < 4; ++ks) s0 = mfma32(kfA[ks], qf[ks], s0);
#pragma unroll
  for (int ks = 0; ks < 4; ++ks) s1 = mfma32(kfB[ks], qf[ks], s1);
  __builtin_amdgcn_s_setprio(0);
  if (maskt) {
#pragma unroll
    for (int r = 0; r < 16; ++r) {
      const int key = k0 + (r & 3) + 8 * (r >> 2) + 4 * hi;
      if (key > qg) s0[r] = -1e30f;
      if (key + 32 > qg) s1[r] = -1e30f;
    }
  }
  float t[16];
#pragma unroll
  for (int r = 0; r < 16; ++r) {
    s0[r] = fexp2(s0[r] - MCONST);
    s1[r] = fexp2(s1[r] - MCONST);
    t[r] = s0[r] + s1[r];
  }
#pragma unroll
  for (int st = 8; st > 0; st >>= 1)
#pragma unroll
    for (int r = 0; r < st; ++r) t[r] += t[r + st];
  l += t[0] + __shfl_xor(t[0], 32);
  bf8 pa[4];
  {
    uint a0 = cvtpk(s0[0], s0[1]), a1 = cvtpk(s0[2], s0[3]);
    uint b0 = cvtpk(s0[4], s0[5]), b1 = cvtpk(s0[6], s0[7]);
    plswap(a0, b0);
    plswap(a1, b1);
    i32x4 w = {(int)a0, (int)a1, (int)b0, (int)b1};
    pa[0] = __builtin_bit_cast(bf8, w);
    uint c0 = cvtpk(s0[8], s0[9]), c1 = cvtpk(s0[10], s0[11]);
    uint d0 = cvtpk(s0[12], s0[13]), d1 = cvtpk(s0[14], s0[15]);
    plswap(c0, d0);
    plswap(c1, d1);
    i32x4 w2 = {(int)c0, (int)c1, (int)d0, (int)d1};
    pa[1] = __builtin_bit_cast(bf8, w2);
  }
  {
    uint a0 = cvtpk(s1[0], s1[1]), a1 = cvtpk(s1[2], s1[3]);
    uint b0 = cvtpk(s1[4], s1[5]), b1 = cvtpk(s1[6], s1[7]);
    plswap(a0, b0);
    plswap(a1, b1);
    i32x4 w = {(int)a0, (int)a1, (int)b0, (int)b1};
    pa[2] = __builtin_bit_cast(bf8, w);
    uint c0 = cvtpk(s1[8], s1[9]), c1 = cvtpk(s1[10], s1[11]);
    uint d0 = cvtpk(s1[12], s1[13]), d1 = cvtpk(s1[14], s1[15]);
    plswap(c0, d0);
    plswap(c1, d1);
    i32x4 w2 = {(int)c0, (int)c1, (int)d0, (int)d1};
    pa[3] = __builtin_bit_cast(bf8, w2);
  }
  __builtin_amdgcn_s_setprio(1);
#pragma unroll
  for (int ks = 0; ks < 4; ++ks) o0 = mfma32(vfA[ks], pa[ks], o0);
#pragma unroll
  for (int ks = 0; ks < 4; ++ks) o1 = mfma32(vfB[ks], pa[ks], o1);
  __builtin_amdgcn_s_setprio(0);
}

__device__ __forceinline__ void tile_out(ushort* ow, const f32x16& o0,
                                         const f32x16& o1, float l, int b,
                                         int h, int qw, int l31, int hi,
                                         int lane, ushort* ao) {
  const float inv = 1.0f / l;
#pragma unroll
  for (int dt = 0; dt < 2; ++dt)
#pragma unroll
    for (int rq = 0; rq < 4; ++rq) {
      const f32x16& ac = dt ? o1 : o0;
      uint2 w;
      w.x = (uint)f2b(ac[rq * 4 + 0] * inv) |
            ((uint)f2b(ac[rq * 4 + 1] * inv) << 16);
      w.y = (uint)f2b(ac[rq * 4 + 2] * inv) |
            ((uint)f2b(ac[rq * 4 + 3] * inv) << 16);
      const int d = dt * 32 + 8 * rq + 4 * hi;
      *(uint2*)&ow[l31 * 66 + d] = w;
    }
  asm volatile("s_waitcnt lgkmcnt(0)" ::: "memory");
  __builtin_amdgcn_sched_barrier(0);
  const int rrow = lane >> 4;
  const int rcol = (lane & 15) * 4;
  const size_t gbase = ((size_t)b * 2048 + qw) * 1024 + h * 64;
#pragma unroll
  for (int i = 0; i < 8; ++i) {
    const int rw = i * 4 + rrow;
    uint2 v = *(const uint2*)&ow[rw * 66 + rcol];
    *(uint2*)&ao[gbase + (size_t)rw * 1024 + rcol] = v;
  }
}

__global__ __launch_bounds__(64) void attn_fwd(const ushort* __restrict__ qh,
                                               const ushort* __restrict__ kh,
                                               const ushort* __restrict__ vT,
                                               ushort* __restrict__ ao) {
  __shared__ ushort kls[4096];  // 8KB K tile (64x64 bf16, swizzled)
  __shared__ ushort vls[4096];  // 8KB V tile (64d x 64k, swizzled)
  const int lane = threadIdx.x;
  const int l31 = lane & 31, hi = lane >> 5;
  const int gid = blockIdx.x;  // 2048
  const int bh = gid & 31;
  const int t = gid >> 5;  // 0..63, 32-row q tile
  const int b = bh >> 4, h = bh & 15;
  const int kv = h >> 2;
  const int n = (32 * t + 95) >> 6;  // KV tiles needed: 1..32
  const int qg = t * 32 + l31;

  const ushort* kbase = kh + (size_t)(b * 4 + kv) * 2048 * 64;
  const ushort* vbase = vT + (size_t)(b * 4 + kv) * 64 * 2048;

  auto stage = [&](int k0) {
#pragma unroll
    for (int jj = 0; jj < 8; ++jj) {
      const int i = jj * 64 + lane;
      const int r = i >> 3, s = i & 7;
      const int sw = (s ^ (r & 7)) << 3;
      gload16(kbase + (size_t)(k0 + r) * 64 + sw, kls + jj * 512);
      gload16(vbase + (size_t)r * 2048 + k0 + sw, vls + jj * 512);
    }
  };

  stage(0);

  bf8 qf[4];
  {
    const ushort* qb = qh + ((size_t)bh * 2048 + qg) * 64 + hi * 8;
#pragma unroll
    for (int ks = 0; ks < 4; ++ks) qf[ks] = *(const bf8*)(qb + ks * 16);
  }

  f32x16 o0 = {}, o1 = {};
  float l = 0.f;
  const int sw0 = l31 & 7;

  for (int it = 0; it < n; ++it) {
    asm volatile("s_waitcnt vmcnt(0)" ::: "memory");
    bf8 kfA[4], kfB[4], vfA[4], vfB[4];
#pragma unroll
    for (int ks = 0; ks < 4; ++ks) {
      const int c2 = 2 * ks + hi;
      const int off = (c2 ^ sw0) << 3;
      kfA[ks] = *(const bf8*)&kls[l31 * 64 + off];
      kfB[ks] = *(const bf8*)&kls[(32 + l31) * 64 + off];
      vfA[ks] = *(const bf8*)&vls[l31 * 64 + off];
      vfB[ks] = *(const bf8*)&vls[(32 + l31) * 64 + off];
    }
    asm volatile("s_waitcnt lgkmcnt(0)" ::: "memory");
    __builtin_amdgcn_sched_barrier(0);
    if (it + 1 < n) stage((it + 1) * 64);  // overwrite is safe: reads drained
    astep2(kfA, kfB, vfA, vfB, qf, o0, o1, l, it * 64, qg, it == n - 1, hi);
  }
  // epilogue reuses K buffer as transpose scratch (staging finished)
  tile_out(kls, o0, o1, l, b, h, t * 32, l31, hi, lane, ao);
}

extern "C" void kernel_launch(void* const* d_in, const int* in_sizes, int n_in,
                              void* d_out, int out_size, void* d_ws,
                              size_t ws_size, hipStream_t stream) {
  (void)in_sizes; (void)n_in; (void)out_size; (void)ws_size;
  const float* x = (const float*)d_in[0];
  const float* wq = (const float*)d_in[1];
  const float* wk = (const float*)d_in[2];
  const float* wv = (const float*)d_in[3];
  const float* wo = (const float*)d_in[4];
  const float* fc = (const float*)d_in[5];
  const float* fs = (const float*)d_in[6];
  float* out = (float*)d_out;

  ushort* xb = (ushort*)d_ws;               // 4096x1024
  ushort* wqkvT = xb + 4194304;             // 1536x1024
  ushort* woT = wqkvT + 1572864;            // 1024x1024
  ushort* qkv = woT + 1048576;              // 4096x1536
  ushort* qh = qkv + 6291456;               // 32x2048x64
  ushort* kh = qh + 4194304;                // 8x2048x64
  ushort* vTb = kh + 1048576;               // 8x64x2048
  ushort* ao = vTb + 1048576;               // 4096x1024

  prep1<<<6656, 256, 0, stream>>>(x, wq, wk, wv, wo, xb, wqkvT, woT);
  gemm_bt<true><<<dim3(12, 32), 256, 0, stream>>>(xb, wqkvT, qkv, 4096, 1536, 1024);
  prep2<<<10496, 256, 0, stream>>>(qkv, fc, fs, qh, kh, vTb);
  attn_fwd<<<2048, 64, 0, stream>>>(qh, kh, vTb, ao);
  gemm_bt<false><<<dim3(8, 32), 256, 0, stream>>>(ao, woT, out, 4096, 1024, 1024);
}